// Round 1
// baseline (95.306 us; speedup 1.0000x reference)
//
#include <hip/hip_runtime.h>

// LIF scan: per neuron i, over t: m = beta*m + x[t,i]; s = (m>=thr);
// spikes[t,i]=s; membranes[t,i]=m; m -= thr*s.
// x: (T, B*N) f32. d_out = [spikes (T*B*N) | membranes (T*B*N)] f32.
// Memory-bound: 128 MiB read + 256 MiB write -> ~64 us floor at 6.3 TB/s.

#define LIF_BETA 0.25f
#define LIF_THR  1.0f
#define LIF_T    32

__global__ __launch_bounds__(256) void lif_scan_kernel(
    const float4* __restrict__ x,
    float4* __restrict__ spikes,
    float4* __restrict__ membranes,
    int bn4)  // (B*N)/4
{
    int i = blockIdx.x * blockDim.x + threadIdx.x;
    if (i >= bn4) return;

    float4 m = make_float4(0.f, 0.f, 0.f, 0.f);

#pragma unroll
    for (int t = 0; t < LIF_T; ++t) {
        size_t idx = (size_t)t * (size_t)bn4 + (size_t)i;
        float4 xv = x[idx];

        m.x = LIF_BETA * m.x + xv.x;
        m.y = LIF_BETA * m.y + xv.y;
        m.z = LIF_BETA * m.z + xv.z;
        m.w = LIF_BETA * m.w + xv.w;

        float4 s;
        s.x = (m.x >= LIF_THR) ? 1.0f : 0.0f;
        s.y = (m.y >= LIF_THR) ? 1.0f : 0.0f;
        s.z = (m.z >= LIF_THR) ? 1.0f : 0.0f;
        s.w = (m.w >= LIF_THR) ? 1.0f : 0.0f;

        spikes[idx] = s;
        membranes[idx] = m;  // recorded BEFORE soft reset

        m.x -= LIF_THR * s.x;
        m.y -= LIF_THR * s.y;
        m.z -= LIF_THR * s.z;
        m.w -= LIF_THR * s.w;
    }
}

extern "C" void kernel_launch(void* const* d_in, const int* in_sizes, int n_in,
                              void* d_out, int out_size, void* d_ws, size_t ws_size,
                              hipStream_t stream) {
    (void)n_in; (void)d_ws; (void)ws_size;

    const float* x = (const float*)d_in[0];
    float* out = (float*)d_out;

    const int total = in_sizes[0];          // T * B * N
    const int bn = total / LIF_T;           // B * N = 1,048,576
    const int bn4 = bn / 4;                 // 262,144

    float* spikes = out;                    // first T*B*N floats
    float* membranes = out + (size_t)total; // second T*B*N floats

    const int block = 256;
    const int grid = (bn4 + block - 1) / block;  // 1024 blocks

    lif_scan_kernel<<<grid, block, 0, stream>>>(
        (const float4*)x, (float4*)spikes, (float4*)membranes, bn4);
}

// Round 2
// 87.934 us; speedup vs baseline: 1.0838x; 1.0838x over previous
//
#include <hip/hip_runtime.h>

// LIF scan: per neuron i, over t: m = beta*m + x[t,i]; s = (m>=thr);
// spikes[t,i]=s; membranes[t,i]=m; m -= thr*s.
// x: (T, B*N) f32. d_out = [spikes (T*B*N) | membranes (T*B*N)] f32.
//
// R1: 95.3us. Traffic arithmetic matched 671MB @ 7.0 TB/s => stores were
// read-allocating (RFO) in L2. Fix: nontemporal (nt) loads+stores to skip
// allocation. Mandatory traffic 402MB @ ~6.9 TB/s => ~58us target.

typedef float f32x4 __attribute__((ext_vector_type(4)));

#define LIF_BETA 0.25f
#define LIF_THR  1.0f
#define LIF_T    32

__global__ __launch_bounds__(256) void lif_scan_kernel(
    const f32x4* __restrict__ x,
    f32x4* __restrict__ spikes,
    f32x4* __restrict__ membranes,
    int bn4)  // (B*N)/4
{
    int i = blockIdx.x * blockDim.x + threadIdx.x;
    if (i >= bn4) return;

    f32x4 m = {0.f, 0.f, 0.f, 0.f};

#pragma unroll
    for (int t = 0; t < LIF_T; ++t) {
        size_t idx = (size_t)t * (size_t)bn4 + (size_t)i;
        f32x4 xv = __builtin_nontemporal_load(&x[idx]);

        m.x = LIF_BETA * m.x + xv.x;
        m.y = LIF_BETA * m.y + xv.y;
        m.z = LIF_BETA * m.z + xv.z;
        m.w = LIF_BETA * m.w + xv.w;

        f32x4 s;
        s.x = (m.x >= LIF_THR) ? 1.0f : 0.0f;
        s.y = (m.y >= LIF_THR) ? 1.0f : 0.0f;
        s.z = (m.z >= LIF_THR) ? 1.0f : 0.0f;
        s.w = (m.w >= LIF_THR) ? 1.0f : 0.0f;

        __builtin_nontemporal_store(s, &spikes[idx]);
        __builtin_nontemporal_store(m, &membranes[idx]);  // pre-reset membrane

        m.x -= LIF_THR * s.x;
        m.y -= LIF_THR * s.y;
        m.z -= LIF_THR * s.z;
        m.w -= LIF_THR * s.w;
    }
}

extern "C" void kernel_launch(void* const* d_in, const int* in_sizes, int n_in,
                              void* d_out, int out_size, void* d_ws, size_t ws_size,
                              hipStream_t stream) {
    (void)n_in; (void)d_ws; (void)ws_size;

    const float* x = (const float*)d_in[0];
    float* out = (float*)d_out;

    const int total = in_sizes[0];          // T * B * N
    const int bn = total / LIF_T;           // B * N = 1,048,576
    const int bn4 = bn / 4;                 // 262,144

    float* spikes = out;                    // first T*B*N floats
    float* membranes = out + (size_t)total; // second T*B*N floats

    const int block = 256;
    const int grid = (bn4 + block - 1) / block;  // 1024 blocks

    lif_scan_kernel<<<grid, block, 0, stream>>>(
        (const f32x4*)x, (f32x4*)spikes, (f32x4*)membranes, bn4);
}